// Round 5
// baseline (272.322 us; speedup 1.0000x reference)
//
#include <hip/hip_runtime.h>
#include <hip/hip_fp16.h>
#include <math.h>

#define LRELU_ALPHA 0.2f
#define NEG_INF -1000000000.0f
#define L2E 1.44269504088896340736f  // log2(e)

constexpr int B_ = 8, N_ = 2048, FIN = 128, FOUT = 64;

typedef _Float16 __attribute__((ext_vector_type(8))) f16x8;
typedef float __attribute__((ext_vector_type(4))) f32x4;

// ---------------------------------------------------------------------------
// Kernel 1 (unchanged, proven): Wh = h @ W^T (fp32), emitted as fp16
// transposed WhT[b][o][n]; also s1 = Wh@a1, s2 = Wh@a2 (fp32).
// ---------------------------------------------------------------------------
__global__ __launch_bounds__(256) void k_wh(
    const float* __restrict__ h, const float* __restrict__ W,
    const float* __restrict__ a, unsigned short* __restrict__ WhT,
    float* __restrict__ s1, float* __restrict__ s2) {
  __shared__ float Wt[128][65];  // [f][o]: read bank (f+o)%32 -> conflict-free
  __shared__ float hs[16][128];

  const int t = threadIdx.x;
  const int row0 = blockIdx.x * 16;

  for (int e = t; e < 64 * 128; e += 256) {
    int o = e >> 7, f = e & 127;
    Wt[f][o] = W[e];
  }
  {
    const float4* hg = (const float4*)(h + (size_t)row0 * FIN);
    for (int i4 = t; i4 < 16 * 32; i4 += 256) {
      int r = i4 >> 5, f4 = i4 & 31;
      *(float4*)&hs[r][f4 * 4] = hg[i4];
    }
  }
  __syncthreads();

  const int wave = t >> 6, lane = t & 63;  // lane = o
  float acc[4] = {0.f, 0.f, 0.f, 0.f};
#pragma unroll 4
  for (int f4 = 0; f4 < 32; ++f4) {
    float w0 = Wt[4 * f4 + 0][lane], w1 = Wt[4 * f4 + 1][lane];
    float w2 = Wt[4 * f4 + 2][lane], w3 = Wt[4 * f4 + 3][lane];
#pragma unroll
    for (int r = 0; r < 4; ++r) {
      float4 hv = *(const float4*)&hs[wave * 4 + r][f4 * 4];
      acc[r] += hv.x * w0 + hv.y * w1 + hv.z * w2 + hv.w * w3;
    }
  }

  const float a1v = a[lane], a2v = a[64 + lane];
  const int b = row0 / N_;
#pragma unroll
  for (int r = 0; r < 4; ++r) {
    const int row = row0 + wave * 4 + r;
    const int n = row - b * N_;
    const float v = acc[r];
    WhT[((size_t)b * 64 + lane) * N_ + n] = __half_as_ushort(__float2half(v));
    float p1 = v * a1v, p2 = v * a2v;
#pragma unroll
    for (int d = 32; d; d >>= 1) {
      p1 += __shfl_xor(p1, d, 64);
      p2 += __shfl_xor(p2, d, 64);
    }
    if (lane == 0) { s1[row] = p1; s2[row] = p2; }
  }
}

// ---------------------------------------------------------------------------
// Kernel 1b: bit-pack adj (134 MB, read once) into per-(row,chunk) u64 masks
// (4.2 MB). Wave reads 64 consecutive ints coalesced, __ballot gives the
// 64-bit mask (bit l = adj[c*64+l] != 0). Stored reordered so consumer lane
// (q,m)'s ushort[q] = { ks0 bits j=q*8..+8 , ks1 bits j=32+q*8..+8 }.
// Pure streaming kernel -> expect ~85% HBM BW like the harness fills.
// ---------------------------------------------------------------------------
__global__ __launch_bounds__(256) void k_pack(
    const int* __restrict__ adj, unsigned long long* __restrict__ pk) {
  const int wave = threadIdx.x >> 6, lane = threadIdx.x & 63;
  const size_t wid = (size_t)blockIdx.x * 4 + wave;  // 8192 waves
  const int* src = adj + wid * 64 * 64 + lane;       // 64 chunks x 64 ints
  unsigned long long* dst = pk + wid * 64;
  for (int it = 0; it < 64; ++it) {
    int v = src[it * 64];
    unsigned long long mask = __ballot(v != 0);
    unsigned long long o = 0;
#pragma unroll
    for (int qq = 0; qq < 4; ++qq) {
      unsigned long long b0 = (mask >> (8 * qq)) & 0xFFull;
      unsigned long long b1 = (mask >> (32 + 8 * qq)) & 0xFFull;
      o |= (b0 | (b1 << 8)) << (16 * qq);
    }
    if (lane == 0) dst[it] = o;
  }
}

// ---------------------------------------------------------------------------
// Kernel 2 v5: BARRIER-FREE all-register pipeline + 2-way j-split.
// Grid (64,8,2) = 1024 blocks -> 4 blocks/CU, 16 waves/CU (2x TLP vs v4).
// Wave = 16 i-rows (rg) x 32 o (p0 pair); j-range = js half, 16 chunks of 64.
// Per chunk per wave: 1 ushort mask load + 4 B-fragment f16x8 loads (all
// L2-resident: packed adj 4.2 MB + WhT 2 MB), s2 from LDS (broadcast).
// Two named slots issued ahead, pinned by asm vmcnt fences (v4-proven
// pattern): steady wait vmcnt(5) = other slot's 5 loads stay in flight.
// No __syncthreads after the s2s publish -- waves free-run.
// Partials (unnormalized acc + row-sum via ones-MFMA) -> pAcc/pSum;
// exact combine in k_norm (fixed -2 shift => partials add exactly).
// ---------------------------------------------------------------------------
__global__ __launch_bounds__(256, 4) void k_attn(
    const unsigned short* __restrict__ WhT,
    const float* __restrict__ s1g, const float* __restrict__ s2g,
    const unsigned short* __restrict__ pk,
    float* __restrict__ pAcc, float* __restrict__ pSum) {
  __shared__ float s2s[N_ / 2];  // this js-half's s2 slice (4 KB)

  const int t = threadIdx.x;
  const int wave = t >> 6, lane = t & 63;
  const int m = lane & 15, q = lane >> 4;
  const int b = blockIdx.y;
  const int i0 = blockIdx.x * 32;
  const int js = blockIdx.z;
  const int j0 = js * (N_ / 2);
  const int rg = wave & 1;         // row-group (rows rg*16..+16)
  const int p0 = (wave >> 1) * 2;  // first o-group of this wave's pair

  // s2 slice, pre-scaled by log2(e); 256 threads x 1 float4 = 1024 floats
  {
    const float4* s2R = (const float4*)(s2g + (size_t)b * N_ + j0);
    float4 v = s2R[t];
    v.x *= L2E; v.y *= L2E; v.z *= L2E; v.w *= L2E;
    ((float4*)s2s)[t] = v;
  }

  const int row_i = i0 + rg * 16 + m;
  const float s1r = s1g[b * N_ + row_i];
  const float c1 = (s1r - 2.0f) * L2E;                // x-2 branch (base-2)
  const float c2 = (LRELU_ALPHA * s1r - 2.0f) * L2E;  // 0.2x-2 branch

  const unsigned short* whB = WhT + (size_t)b * 64 * N_;
  const unsigned short* bp0 = whB + (size_t)(p0 * 16 + m) * N_ + j0 + q * 8;
  const unsigned short* bp1 = whB + (size_t)((p0 + 1) * 16 + m) * N_ + j0 + q * 8;
  // packed masks: ushort index ((row*32 + c)*4 + q), c = js*16 + lc
  const unsigned short* pkL =
      pk + ((size_t)(b * N_ + row_i) * 32 + js * 16) * 4 + q;

  f16x8 ones;
#pragma unroll
  for (int j = 0; j < 8; ++j) ones[j] = (_Float16)1.0f;

  __syncthreads();  // publish s2s; the only barrier

  f32x4 acc0 = {0.f, 0.f, 0.f, 0.f}, acc1 = acc0, accS = acc0;

  // named slot registers (rule #20: no runtime-indexed arrays)
  unsigned sA_w, sB_w;
  f16x8 sA_b00, sA_b01, sA_b10, sA_b11;
  f16x8 sB_b00, sB_b01, sB_b10, sB_b11;

#define ISSUE(P, c)                                  \
  {                                                  \
    P##_w = (unsigned)pkL[(c) * 4];                  \
    P##_b00 = *(const f16x8*)(bp0 + (c) * 64);       \
    P##_b01 = *(const f16x8*)(bp0 + (c) * 64 + 32);  \
    P##_b10 = *(const f16x8*)(bp1 + (c) * 64);       \
    P##_b11 = *(const f16x8*)(bp1 + (c) * 64 + 32);  \
  }
#define CONSUME(P, c)                                                        \
  {                                                                          \
    _Pragma("unroll") for (int ks = 0; ks < 2; ++ks) {                       \
      const float* sp = &s2s[(c) * 64 + ks * 32 + q * 8];                    \
      float4 sv0 = *(const float4*)sp;                                       \
      float4 sv1 = *(const float4*)(sp + 4);                                 \
      float xs[8] = {sv0.x, sv0.y, sv0.z, sv0.w, sv1.x, sv1.y, sv1.z, sv1.w};\
      unsigned wb = P##_w >> (ks * 8);                                       \
      f16x8 af;                                                              \
      _Pragma("unroll") for (int j = 0; j < 8; ++j) {                        \
        float x = xs[j];                                                     \
        float e = fmaxf(c1 + x, fmaf(LRELU_ALPHA, x, c2));                   \
        e = ((wb >> j) & 1u) ? e : NEG_INF;                                  \
        af[j] = (_Float16)__builtin_amdgcn_exp2f(e);  /* masked -> 0 */      \
      }                                                                      \
      f16x8 B0 = ks ? P##_b01 : P##_b00;                                     \
      f16x8 B1 = ks ? P##_b11 : P##_b10;                                     \
      acc0 = __builtin_amdgcn_mfma_f32_16x16x32_f16(af, B0, acc0, 0, 0, 0);  \
      acc1 = __builtin_amdgcn_mfma_f32_16x16x32_f16(af, B1, acc1, 0, 0, 0);  \
      accS = __builtin_amdgcn_mfma_f32_16x16x32_f16(af, ones, accS, 0, 0, 0);\
    }                                                                        \
  }
#define FENCE(VMS) asm volatile("s_waitcnt " VMS ::: "memory");

  ISSUE(sA, 0)
  ISSUE(sB, 1)
  for (int c = 0; c < 14; c += 2) {
    FENCE("vmcnt(5)")          // slot A's 5 loads landed (B's in flight)
    CONSUME(sA, c) ISSUE(sA, c + 2)
    FENCE("vmcnt(5)")
    CONSUME(sB, c + 1) ISSUE(sB, c + 3)   // last issue: chunk 15 at c=12
  }
  FENCE("vmcnt(5)")
  CONSUME(sA, 14)
  FENCE("vmcnt(0)")
  CONSUME(sB, 15)

  // C/D layout: row_in_tile = q*4 + r, col = m; accS[r] = rowsum(q*4+r)
#pragma unroll
  for (int r = 0; r < 4; ++r) {
    const int ri = q * 4 + r;
    const size_t row = (size_t)js * B_ * N_ + (size_t)b * N_ + i0 + rg * 16 + ri;
    pAcc[row * FOUT + (p0 + 0) * 16 + m] = acc0[r];
    pAcc[row * FOUT + (p0 + 1) * 16 + m] = acc1[r];
    if (p0 == 0 && m == 0) pSum[row] = accS[r];
  }
#undef ISSUE
#undef CONSUME
#undef FENCE
}

// ---------------------------------------------------------------------------
// Kernel 3: combine j-halves and normalize. out = (accA+accB)/(lA+lB).
// ---------------------------------------------------------------------------
__global__ __launch_bounds__(256) void k_norm(
    const float* __restrict__ pAcc, const float* __restrict__ pSum,
    float* __restrict__ out) {
  const int i4 = blockIdx.x * 256 + threadIdx.x;  // float4 index, 262144 total
  const int row = i4 >> 4;                        // 16 float4 per row
  float4 v0 = ((const float4*)pAcc)[i4];
  float4 v1 = ((const float4*)pAcc)[i4 + B_ * N_ * FOUT / 4];
  const float l = pSum[row] + pSum[B_ * N_ + row];
  const float inv = (l == 0.f) ? 1.f : 1.f / l;  // fully-masked row guard
  float4 o;
  o.x = (v0.x + v1.x) * inv;
  o.y = (v0.y + v1.y) * inv;
  o.z = (v0.z + v1.z) * inv;
  o.w = (v0.w + v1.w) * inv;
  ((float4*)out)[i4] = o;
}

extern "C" void kernel_launch(void* const* d_in, const int* in_sizes, int n_in,
                              void* d_out, int out_size, void* d_ws, size_t ws_size,
                              hipStream_t stream) {
  const float* h   = (const float*)d_in[0];
  const int*   adj = (const int*)d_in[1];
  const float* W   = (const float*)d_in[2];
  const float* a   = (const float*)d_in[3];
  float* out = (float*)d_out;

  // ws: WhT fp16 (2 MB) | s1 (64 KB) | s2 (64 KB) | pAcc (8 MB) |
  //     pSum (128 KB) | packed adj (4.2 MB)
  unsigned short* WhT = (unsigned short*)d_ws;
  float* s1 = (float*)(WhT + (size_t)B_ * 64 * N_);
  float* s2 = s1 + (size_t)B_ * N_;
  float* pAcc = s2 + (size_t)B_ * N_;
  float* pSum = pAcc + (size_t)2 * B_ * N_ * FOUT;
  unsigned long long* pkw = (unsigned long long*)(pSum + (size_t)2 * B_ * N_);

  k_pack<<<dim3(2048), 256, 0, stream>>>(adj, pkw);
  k_wh<<<dim3(B_ * N_ / 16), 256, 0, stream>>>(h, W, a, WhT, s1, s2);
  k_attn<<<dim3(N_ / 32, B_, 2), 256, 0, stream>>>(
      WhT, s1, s2, (const unsigned short*)pkw, pAcc, pSum);
  k_norm<<<dim3(B_ * N_ * FOUT / 1024), 256, 0, stream>>>(pAcc, pSum, out);
}

// Round 6
// 236.540 us; speedup vs baseline: 1.1513x; 1.1513x over previous
//
#include <hip/hip_runtime.h>
#include <hip/hip_fp16.h>
#include <math.h>

#define LRELU_ALPHA 0.2f
#define NEG_INF -1000000000.0f
#define L2E 1.44269504088896340736f  // log2(e)

constexpr int B_ = 8, N_ = 2048, FIN = 128, FOUT = 64;

typedef _Float16 __attribute__((ext_vector_type(8))) f16x8;
typedef float __attribute__((ext_vector_type(4))) f32x4;

// async global->LDS, 16B per lane; lane l's data lands at ldsbase + l*16
__device__ __forceinline__ void gload16(const void* g, void* l) {
  __builtin_amdgcn_global_load_lds(
      (const __attribute__((address_space(1))) void*)g,
      (__attribute__((address_space(3))) void*)l, 16, 0, 0);
}

// ---------------------------------------------------------------------------
// Kernel 1 (unchanged, proven): Wh = h @ W^T (fp32), emitted as fp16
// transposed WhT[b][o][n]; also s1 = Wh@a1, s2 = Wh@a2 (fp32).
// ---------------------------------------------------------------------------
__global__ __launch_bounds__(256) void k_wh(
    const float* __restrict__ h, const float* __restrict__ W,
    const float* __restrict__ a, unsigned short* __restrict__ WhT,
    float* __restrict__ s1, float* __restrict__ s2) {
  __shared__ float Wt[128][65];  // [f][o]: read bank (f+o)%32 -> conflict-free
  __shared__ float hs[16][128];

  const int t = threadIdx.x;
  const int row0 = blockIdx.x * 16;

  for (int e = t; e < 64 * 128; e += 256) {
    int o = e >> 7, f = e & 127;
    Wt[f][o] = W[e];
  }
  {
    const float4* hg = (const float4*)(h + (size_t)row0 * FIN);
    for (int i4 = t; i4 < 16 * 32; i4 += 256) {
      int r = i4 >> 5, f4 = i4 & 31;
      *(float4*)&hs[r][f4 * 4] = hg[i4];
    }
  }
  __syncthreads();

  const int wave = t >> 6, lane = t & 63;  // lane = o
  float acc[4] = {0.f, 0.f, 0.f, 0.f};
#pragma unroll 4
  for (int f4 = 0; f4 < 32; ++f4) {
    float w0 = Wt[4 * f4 + 0][lane], w1 = Wt[4 * f4 + 1][lane];
    float w2 = Wt[4 * f4 + 2][lane], w3 = Wt[4 * f4 + 3][lane];
#pragma unroll
    for (int r = 0; r < 4; ++r) {
      float4 hv = *(const float4*)&hs[wave * 4 + r][f4 * 4];
      acc[r] += hv.x * w0 + hv.y * w1 + hv.z * w2 + hv.w * w3;
    }
  }

  const float a1v = a[lane], a2v = a[64 + lane];
  const int b = row0 / N_;
#pragma unroll
  for (int r = 0; r < 4; ++r) {
    const int row = row0 + wave * 4 + r;
    const int n = row - b * N_;
    const float v = acc[r];
    WhT[((size_t)b * 64 + lane) * N_ + n] = __half_as_ushort(__float2half(v));
    float p1 = v * a1v, p2 = v * a2v;
#pragma unroll
    for (int d = 32; d; d >>= 1) {
      p1 += __shfl_xor(p1, d, 64);
      p2 += __shfl_xor(p2, d, 64);
    }
    if (lane == 0) { s1[row] = p1; s2[row] = p2; }
  }
}

// ---------------------------------------------------------------------------
// Kernel 2 v6: same proven DMA-LDS machinery as v3b, re-tiled for occupancy.
// Block = 16 i-rows x 64 o, grid (B, N/16) = 1024 blocks -> 4 blocks/CU
// (v3b's grid 512 hard-capped residency at 2/CU; round-1 counters showed
// pure latency-bound: Occ 21%, all pipes idle). gridDim.x = batch -> each
// XCD's L2 privately holds one batch's WhT (2 MB) + s2 row.
// Wave w owns o-group w (16 cols), all 16 rows. Chunk = 64 j: adj 16x64
// (4 KB) + WhT 64x64 fp16 (8 KB) = 12 DMA instrs, 3 per wave. 2 buffers
// (24 KB) + s2s (8 KB) = 32 KB LDS = exactly the 4-blocks/CU budget.
// Steady iteration: consume(c) | bar | STAGE(c+2) | vmcnt(3) | bar
// (counted wait: chunk c+1's 3 own DMAs stay in flight; barrier makes the
// guarantee collective, v3b-proven). Two barriers/chunk needed at depth 1
// (consume-before-overwrite hazard); 16 waves/CU absorb convoy stalls.
// Row sums via ones-MFMA (accS); exp in base-2 with folded constants.
// ---------------------------------------------------------------------------
__global__ __launch_bounds__(256, 4) void k_attn(
    const unsigned short* __restrict__ WhT,
    const float* __restrict__ s1g, const float* __restrict__ s2g,
    const int* __restrict__ adj, float* __restrict__ out) {
  __shared__ __align__(16) unsigned char sbuf[2][12 * 1024];
  __shared__ float s2s[N_];

  const int t = threadIdx.x;
  const int wave = t >> 6, lane = t & 63;
  const int m = lane & 15, q = lane >> 4;
  const int b = blockIdx.x;        // = XCD id under round-robin dispatch
  const int i0 = blockIdx.y * 16;

  const int* adjB = adj + (size_t)b * N_ * N_;
  const unsigned short* whB = WhT + (size_t)b * 64 * N_;

  // preload s2 row (8 KB), pre-scaled by log2(e)
  {
    const float4* s2R = (const float4*)(s2g + (size_t)b * N_);
    for (int i = t; i < N_ / 4; i += 256) {
      float4 v = s2R[i];
      v.x *= L2E; v.y *= L2E; v.z *= L2E; v.w *= L2E;
      ((float4*)s2s)[i] = v;
    }
  }

  // A-fragment: lane (q,m) holds A[row=m][k=q*8..+8] -> s1 of row i0+m
  const float s1r = s1g[b * N_ + i0 + m];
  const float c1 = (s1r - 2.0f) * L2E;                // x-2 branch (base-2)
  const float c2 = (LRELU_ALPHA * s1r - 2.0f) * L2E;  // 0.2x-2 branch

  f16x8 ones;
#pragma unroll
  for (int j = 0; j < 8; ++j) ones[j] = (_Float16)1.0f;

  // 12 DMA instrs per chunk, wave w does global instrs {3w, 3w+1, 3w+2}.
  //  j<4  : adj, (ks=j>>1, h=j&1): src = adjB[(i0+m)*N + ks*32 + q*8 + h*4]
  //  j>=4 : WhT, (g=(j-4)>>1, ks=(j-4)&1): src = whB[(g*16+m)*N + ks*32 + q*8]
  // LDS slot = j*1024 + lane*16 (consumed linearly: conflict-free).
  const unsigned char* gp[3];
  int gs[3];
#pragma unroll
  for (int s = 0; s < 3; ++s) {
    const int j = wave * 3 + s;
    if (j < 4) {
      const int ks = j >> 1, hh = j & 1;
      gp[s] = (const unsigned char*)(adjB + (size_t)(i0 + m) * N_ +
                                     ks * 32 + q * 8 + hh * 4);
      gs[s] = 64 * 4;  // 64 ints per chunk
    } else {
      const int g = (j - 4) >> 1, ks = (j - 4) & 1;
      gp[s] = (const unsigned char*)(whB + (size_t)(g * 16 + m) * N_ +
                                     ks * 32 + q * 8);
      gs[s] = 64 * 2;  // 64 fp16 per chunk
    }
  }

#define STAGE(S, c)                                                         \
  {                                                                         \
    _Pragma("unroll") for (int s = 0; s < 3; ++s)                           \
        gload16(gp[s] + (size_t)(c) * gs[s],                                \
                (S) + (wave * 3 + s) * 1024 + lane * 16);                   \
  }

  f32x4 acc = {0.f, 0.f, 0.f, 0.f}, accS = acc;

  auto consume = [&](const unsigned char* base, int c) {
#pragma unroll
    for (int ks = 0; ks < 2; ++ks) {
      int4 A0 = *(const int4*)(base + (ks * 2 + 0) * 1024 + lane * 16);
      int4 A1 = *(const int4*)(base + (ks * 2 + 1) * 1024 + lane * 16);
      const float* sp = &s2s[c * 64 + ks * 32 + q * 8];
      float4 sv0 = *(const float4*)sp;
      float4 sv1 = *(const float4*)(sp + 4);
      float xs[8] = {sv0.x, sv0.y, sv0.z, sv0.w, sv1.x, sv1.y, sv1.z, sv1.w};
      int avs[8] = {A0.x, A0.y, A0.z, A0.w, A1.x, A1.y, A1.z, A1.w};
      f16x8 af;
#pragma unroll
      for (int j = 0; j < 8; ++j) {
        float x = xs[j];
        float e = fmaxf(c1 + x, fmaf(LRELU_ALPHA, x, c2));
        e = avs[j] ? e : NEG_INF;
        af[j] = (_Float16)__builtin_amdgcn_exp2f(e);  // masked -> exactly 0
      }
      f16x8 bf =
          *(const f16x8*)(base + (4 + wave * 2 + ks) * 1024 + lane * 16);
      acc = __builtin_amdgcn_mfma_f32_16x16x32_f16(af, bf, acc, 0, 0, 0);
      accS = __builtin_amdgcn_mfma_f32_16x16x32_f16(af, ones, accS, 0, 0, 0);
    }
  };

  // prologue: chunks 0,1 staged; full drain once (also publishes s2s)
  STAGE(sbuf[0], 0)
  STAGE(sbuf[1], 1)
  __syncthreads();

  for (int c = 0; c < 30; ++c) {
    consume(sbuf[c & 1], c);
    __builtin_amdgcn_s_barrier();         // all waves done reading buf c&1
    STAGE(sbuf[c & 1], c + 2)             // overwrite it with chunk c+2
    asm volatile("s_waitcnt vmcnt(3)" ::: "memory");  // own chunk-(c+1) landed
    __builtin_amdgcn_s_barrier();         // => everyone's chunk c+1 landed
  }
  consume(sbuf[0], 30);
  asm volatile("s_waitcnt vmcnt(0)" ::: "memory");
  __builtin_amdgcn_s_barrier();
  consume(sbuf[1], 31);

  // C/D layout: row_in_tile = q*4 + r, col = m.
  // accS[r] = rowsum(q*4+r) broadcast across cols -> direct normalizer.
#pragma unroll
  for (int r = 0; r < 4; ++r) {
    const float l = accS[r];
    const float inv = (l == 0.f) ? 1.f : 1.f / l;  // fully-masked row guard
    const size_t row = (size_t)b * N_ + i0 + q * 4 + r;
    out[row * FOUT + wave * 16 + m] = acc[r] * inv;
  }
#undef STAGE
}

extern "C" void kernel_launch(void* const* d_in, const int* in_sizes, int n_in,
                              void* d_out, int out_size, void* d_ws, size_t ws_size,
                              hipStream_t stream) {
  const float* h   = (const float*)d_in[0];
  const int*   adj = (const int*)d_in[1];
  const float* W   = (const float*)d_in[2];
  const float* a   = (const float*)d_in[3];
  float* out = (float*)d_out;

  // ws: WhT fp16 (2 MB) | s1 (64 KB) | s2 (64 KB)
  unsigned short* WhT = (unsigned short*)d_ws;
  float* s1 = (float*)(WhT + (size_t)B_ * 64 * N_);
  float* s2 = s1 + (size_t)B_ * N_;

  k_wh<<<dim3(B_ * N_ / 16), 256, 0, stream>>>(h, W, a, WhT, s1, s2);
  k_attn<<<dim3(B_, N_ / 16), 256, 0, stream>>>(WhT, s1, s2, adj, out);
}